// Round 10
// baseline (443.388 us; speedup 1.0000x reference)
//
#include <hip/hip_runtime.h>

#define Bz 8
#define Nn 2048
#define Cc 128
#define KK 16
#define WD 512
#define F2 64
#define FO 128
#define NP (Bz*Nn)
#define SQ2 1.41421356237309515f
#define HSTRIDE 136   // padded bf16 row stride (16B-aligned)
#define CAPMAX 256

// ws layout (float offsets)
#define GOFF   ((size_t)0)
#define BEOFF  ((size_t)1024)
#define LSOFF  ((size_t)2048)
#define HOFF   ((size_t)3072)
#define SQOFF  (HOFF + (size_t)NP*Cc)
#define A1OFF  (SQOFF + (size_t)NP)
#define ADOFF  (A1OFF + (size_t)NP*F2)
#define HXOFF  (ADOFF + (size_t)NP*Cc)
#define IXOFF  (HXOFF + (size_t)NP*Cc)
#define CNTOFF (IXOFF + (size_t)NP*KK)
#define FBNOFF (CNTOFF + (size_t)NP)
#define FBQOFF (FBNOFF + (size_t)64)
// byte offsets for the u16 arrays
#define HIBYTES   ((FBQOFF + (size_t)NP) * 4)
#define W2TBYTES  (HIBYTES + (size_t)NP*HSTRIDE*2)     // bf16 W2^T  [128][64]
#define WX2TBYTES (W2TBYTES + (size_t)128*64*2)        // bf16 Wx2^T [128][128]
#define CANDBYTES (WX2TBYTES + (size_t)128*128*2)

typedef __attribute__((ext_vector_type(8))) short bf16x8;
typedef __attribute__((ext_vector_type(4))) float f32x4;

__device__ __forceinline__ unsigned short f2bf(float f) {
  unsigned u = __float_as_uint(f);
  unsigned r = (u + 0x7FFFu + ((u >> 16) & 1u)) >> 16;
  return (unsigned short)r;
}
__device__ __forceinline__ float lrelu(float v) {
  return (v > 0.f ? v : 0.2f*v) * SQ2;
}

// ---------------------------------------------------------------------------
// Kernel 1: per-batch FiLM vectors
__global__ __launch_bounds__(512) void k_pervec(const float* __restrict__ w,
    const float* __restrict__ Wg, const float* __restrict__ Wb,
    const float* __restrict__ Wls, const float* __restrict__ bls,
    float* __restrict__ ws) {
  __shared__ float red[3][4][Cc];
  const int b = blockIdx.x;
  const int c = threadIdx.x & 127, dc = threadIdx.x >> 7;
  const float* wr = w + b*WD;
  float ag = 0.f, ab = 0.f, al = 0.f;
  for (int d = dc*128; d < dc*128 + 128; ++d) {
    float wv = wr[d];
    ag = fmaf(wv, Wg[d*Cc + c], ag);
    ab = fmaf(wv, Wb[d*Cc + c], ab);
    al = fmaf(wv, Wls[d*Cc + c], al);
  }
  red[0][dc][c] = ag; red[1][dc][c] = ab; red[2][dc][c] = al;
  __syncthreads();
  if (dc == 0) {
    float sg = red[0][0][c] + red[0][1][c] + red[0][2][c] + red[0][3][c];
    float sb = red[1][0][c] + red[1][1][c] + red[1][2][c] + red[1][3][c];
    float sl = red[2][0][c] + red[2][1][c] + red[2][2][c] + red[2][3][c];
    ws[GOFF  + b*Cc + c] = 1.0f + sg;
    ws[BEOFF + b*Cc + c] = sb;
    ws[LSOFF + b*Cc + c] = sl + bls[c];
  }
}

// ---------------------------------------------------------------------------
// Kernel 1b: bf16-transposed weight copies for the MFMA MLP.
__global__ __launch_bounds__(256) void k_wprep(const float* __restrict__ W2,
    const float* __restrict__ Wx2, unsigned short* __restrict__ w2t,
    unsigned short* __restrict__ wx2t) {
  int idx = blockIdx.x*256 + threadIdx.x;
  if (idx < 128*64)  { int c = idx >> 6, j = idx & 63;  w2t[idx]  = f2bf(W2[j*FO + c]); }
  if (idx < 128*128) { int c = idx >> 7, j = idx & 127; wx2t[idx] = f2bf(Wx2[j*FO + c]); }
}

// ---------------------------------------------------------------------------
// Kernel 2: h = LN(x)*g + beta, sq = sum(h*h), hi = bf16(h); zero fb queue.
__global__ __launch_bounds__(64) void k_h(const float* __restrict__ x,
                                          float* __restrict__ ws,
                                          unsigned short* __restrict__ hi_g,
                                          int* __restrict__ fbn) {
  const int n = blockIdx.x;
  const int b = n >> 11;
  const int t = threadIdx.x;
  if (n == 0 && t == 0) fbn[0] = 0;
  const float* xr = x + (size_t)n*Cc;
  float x0 = xr[t], x1 = xr[t + 64];
  float s = x0 + x1, ss = x0*x0 + x1*x1;
  #pragma unroll
  for (int m = 1; m < 64; m <<= 1) {
    s  += __shfl_xor(s,  m, 64);
    ss += __shfl_xor(ss, m, 64);
  }
  float mu  = s * (1.0f/128.0f);
  float var = ss * (1.0f/128.0f) - mu*mu;
  float rs  = rsqrtf(var + 1e-5f);
  float h0 = (x0 - mu)*rs*ws[GOFF + b*Cc + t]      + ws[BEOFF + b*Cc + t];
  float h1 = (x1 - mu)*rs*ws[GOFF + b*Cc + t + 64] + ws[BEOFF + b*Cc + t + 64];
  float* hr = ws + HOFF + (size_t)n*Cc;
  hr[t] = h0; hr[t + 64] = h1;
  hi_g[(size_t)n*HSTRIDE + t]      = f2bf(h0);
  hi_g[(size_t)n*HSTRIDE + t + 64] = f2bf(h1);
  float q = h0*h0 + h1*h1;
  #pragma unroll
  for (int m = 1; m < 64; m <<= 1) q += __shfl_xor(q, m, 64);
  if (t == 0) ws[SQOFF + n] = q;
}

// ---------------------------------------------------------------------------
// Kernel 3: precompute A1 = h@W1, Ad = h@Wx1[128:], hxb = h@Wx1[:128]-Ad+bx1
__global__ __launch_bounds__(128) void k_pre(const float* __restrict__ W1,
    const float* __restrict__ Wx1, const float* __restrict__ bx1,
    float* __restrict__ ws) {
  __shared__ float hs[4][Cc];
  const int t = threadIdx.x;
  const size_t row0 = (size_t)blockIdx.x * 4;
  const float* h = ws + HOFF;
  #pragma unroll
  for (int r = 0; r < 4; ++r) hs[r][t] = h[(row0 + r)*Cc + t];
  __syncthreads();
  float ad[4] = {0,0,0,0}, ac[4] = {0,0,0,0};
  for (int cp = 0; cp < Cc; ++cp) {
    float whi = Wx1[cp*FO + t];
    float wlo = Wx1[(Cc + cp)*FO + t];
    #pragma unroll
    for (int r = 0; r < 4; ++r) {
      float hv = hs[r][cp];
      ac[r] = fmaf(hv, whi, ac[r]);
      ad[r] = fmaf(hv, wlo, ad[r]);
    }
  }
  float bx = bx1[t];
  #pragma unroll
  for (int r = 0; r < 4; ++r) {
    ws[ADOFF + (row0 + r)*Cc + t] = ad[r];
    ws[HXOFF + (row0 + r)*Cc + t] = ac[r] - ad[r] + bx;
  }
  const int j = t & 63, rp = t >> 6;
  float a0 = 0.f, a1 = 0.f;
  for (int cp = 0; cp < Cc; ++cp) {
    float wv = W1[cp*F2 + j];
    a0 = fmaf(hs[rp][cp],     wv, a0);
    a1 = fmaf(hs[rp + 2][cp], wv, a1);
  }
  ws[A1OFF + (row0 + rp)*F2 + j]     = a0;
  ws[A1OFF + (row0 + rp + 2)*F2 + j] = a1;
}

// ---------------------------------------------------------------------------
// Kernel 4: MFMA approx distances + tau-filter compaction. (unchanged)
__global__ __launch_bounds__(512, 4) void k_filter(float* __restrict__ ws,
    const unsigned short* __restrict__ hi_g, unsigned short* __restrict__ cand,
    int* __restrict__ cnt_g, int CAP) {
  __shared__ unsigned short hiA[32*HSTRIDE];
  __shared__ float smB[8704];
  __shared__ float sqA[32], sqB[128], tauS[32];
  __shared__ int cnt[32];
  unsigned short* hB = (unsigned short*)smB;
  float* dstage = smB;
  const int t = threadIdx.x;
  const int b  = blockIdx.x >> 6;
  const int i0 = (blockIdx.x & 63) << 5;
  const int wave = t >> 6, lane = t & 63;
  const int wi = wave & 1, wj = wave >> 1;
  const int l15 = lane & 15, l4 = lane >> 4;
  const float* __restrict__ sq = ws + SQOFF + (size_t)b*Nn;
  const unsigned short* __restrict__ hib = hi_g + (size_t)b*Nn*HSTRIDE;

  { int r = t >> 4, o = (t & 15) * 8;
    *(bf16x8*)&hiA[r*HSTRIDE + o] = *(const bf16x8*)&hib[(size_t)(i0 + r)*HSTRIDE + o];
  }
  if (t < 32) { sqA[t] = sq[i0 + t]; cnt[t] = 0; }

  float samp[4][8];

  for (int jt = 0; jt < 4; ++jt) {
    const int j0 = jt << 7;
    __syncthreads();
    { int r = t >> 2, o = (t & 3) * 32;
      #pragma unroll
      for (int q = 0; q < 4; ++q)
        *(bf16x8*)&hB[r*HSTRIDE + o + q*8] =
            *(const bf16x8*)&hib[(size_t)(j0 + r)*HSTRIDE + o + q*8];
    }
    if (t < 128) sqB[t] = sq[j0 + t];
    __syncthreads();
    f32x4 acc0 = {0,0,0,0}, acc1 = {0,0,0,0};
    #pragma unroll
    for (int kb = 0; kb < 4; ++kb) {
      const int cbase = kb*32 + l4*8;
      bf16x8 a  = *(const bf16x8*)&hiA[(16*wi + l15)*HSTRIDE + cbase];
      bf16x8 b0 = *(const bf16x8*)&hB [(32*wj      + l15)*HSTRIDE + cbase];
      bf16x8 b1 = *(const bf16x8*)&hB [(32*wj + 16 + l15)*HSTRIDE + cbase];
      acc0 = __builtin_amdgcn_mfma_f32_16x16x32_bf16(a, b0, acc0, 0, 0, 0);
      acc1 = __builtin_amdgcn_mfma_f32_16x16x32_bf16(a, b1, acc1, 0, 0, 0);
    }
    __syncthreads();
    #pragma unroll
    for (int jb = 0; jb < 2; ++jb) {
      const f32x4 a = jb ? acc1 : acc0;
      #pragma unroll
      for (int r = 0; r < 4; ++r) {
        int il = 16*wi + l4*4 + r;
        int jl = 32*wj + 16*jb + l15;
        dstage[il*132 + jl] = sqA[il] + sqB[jl] - 2.f*a[r];
      }
    }
    __syncthreads();
    #pragma unroll
    for (int r = 0; r < 4; ++r) {
      int row = wave*4 + r;
      samp[r][jt*2]     = dstage[row*132 + lane];
      samp[r][jt*2 + 1] = dstage[row*132 + 64 + lane];
    }
  }

  {
    float lo[4], hi[4];
    #pragma unroll
    for (int r = 0; r < 4; ++r) {
      float m = samp[r][0];
      #pragma unroll
      for (int k = 1; k < 8; ++k) m = fmaxf(m, samp[r][k]);
      #pragma unroll
      for (int s2 = 1; s2 < 64; s2 <<= 1) m = fmaxf(m, __shfl_xor(m, s2, 64));
      hi[r] = fmaxf(m, 0.f)*1.0001f + 1e-6f;
      lo[r] = 0.f;
    }
    #pragma unroll 1
    for (int it = 0; it < 18; ++it) {
      float mid[4], cv[4];
      #pragma unroll
      for (int r = 0; r < 4; ++r) {
        mid[r] = 0.5f*(lo[r] + hi[r]);
        float c = 0.f;
        #pragma unroll
        for (int k = 0; k < 8; ++k) c += (samp[r][k] < mid[r]) ? 1.f : 0.f;
        cv[r] = c;
      }
      #pragma unroll
      for (int s2 = 1; s2 < 64; s2 <<= 1) {
        #pragma unroll
        for (int r = 0; r < 4; ++r) cv[r] += __shfl_xor(cv[r], s2, 64);
      }
      #pragma unroll
      for (int r = 0; r < 4; ++r) {
        bool ge = cv[r] >= 20.f;
        hi[r] = ge ? mid[r] : hi[r];
        lo[r] = ge ? lo[r] : mid[r];
      }
    }
    if (lane == 0) {
      #pragma unroll
      for (int r = 0; r < 4; ++r) tauS[wave*4 + r] = hi[r];
    }
    __syncthreads();
    #pragma unroll
    for (int r = 0; r < 4; ++r) {
      int row = wave*4 + r;
      float tv = hi[r];
      size_t rg = (size_t)(b*Nn + i0 + row);
      #pragma unroll
      for (int k = 0; k < 8; ++k) {
        if (samp[r][k] < tv) {
          int j = (k >> 1)*128 + (k & 1)*64 + lane;
          int pos = atomicAdd(&cnt[row], 1);
          if (pos < CAP) cand[rg*CAPMAX + pos] = (unsigned short)j;
        }
      }
    }
  }

  for (int jt = 4; jt < 16; ++jt) {
    const int j0 = jt << 7;
    __syncthreads();
    { int r = t >> 2, o = (t & 3) * 32;
      #pragma unroll
      for (int q = 0; q < 4; ++q)
        *(bf16x8*)&hB[r*HSTRIDE + o + q*8] =
            *(const bf16x8*)&hib[(size_t)(j0 + r)*HSTRIDE + o + q*8];
    }
    if (t < 128) sqB[t] = sq[j0 + t];
    __syncthreads();
    f32x4 acc0 = {0,0,0,0}, acc1 = {0,0,0,0};
    #pragma unroll
    for (int kb = 0; kb < 4; ++kb) {
      const int cbase = kb*32 + l4*8;
      bf16x8 a  = *(const bf16x8*)&hiA[(16*wi + l15)*HSTRIDE + cbase];
      bf16x8 b0 = *(const bf16x8*)&hB [(32*wj      + l15)*HSTRIDE + cbase];
      bf16x8 b1 = *(const bf16x8*)&hB [(32*wj + 16 + l15)*HSTRIDE + cbase];
      acc0 = __builtin_amdgcn_mfma_f32_16x16x32_bf16(a, b0, acc0, 0, 0, 0);
      acc1 = __builtin_amdgcn_mfma_f32_16x16x32_bf16(a, b1, acc1, 0, 0, 0);
    }
    #pragma unroll
    for (int jb = 0; jb < 2; ++jb) {
      const f32x4 a = jb ? acc1 : acc0;
      #pragma unroll
      for (int r = 0; r < 4; ++r) {
        int il = 16*wi + l4*4 + r;
        int jl = 32*wj + 16*jb + l15;
        float dv = sqA[il] + sqB[jl] - 2.f*a[r];
        if (dv < tauS[il]) {
          int pos = atomicAdd(&cnt[il], 1);
          if (pos < CAP)
            cand[(size_t)(b*Nn + i0 + il)*CAPMAX + pos] = (unsigned short)(j0 + jl);
        }
      }
    }
  }
  __syncthreads();
  if (t < 32) cnt_g[b*Nn + i0 + t] = cnt[t];
}

// ---------------------------------------------------------------------------
// Kernel 5: exact fp32 refine + fb-queue append. XCD-swizzled. (unchanged)
__global__ __launch_bounds__(256) void k_refine(float* __restrict__ ws,
    const unsigned short* __restrict__ cand, const int* __restrict__ cnt_g,
    int* __restrict__ fbn, int* __restrict__ fbq, int CAP) {
  __shared__ float dsh[4][CAPMAX];
  __shared__ unsigned short cjs[4][CAPMAX];
  const int wave = threadIdx.x >> 6, lane = threadIdx.x & 63;
  const int s8 = lane >> 3, ch = lane & 7;
  const int blk = blockIdx.x;
  const int row = ((blk & 7)*512 + (blk >> 3))*4 + wave;
  const int b = row >> 11;
  const float* __restrict__ h = ws + HOFF;
  int c_ = cnt_g[row];
  int cm = (c_ < 17 || c_ > CAP) ? 0 : c_;
  if (cm == 0 && lane == 0) { int q = atomicAdd(fbn, 1); fbq[q] = row; }
  for (int cc = lane; cc < cm; cc += 64)
    cjs[wave][cc] = cand[(size_t)row*CAPMAX + cc];
  float4 hi4[4];
  #pragma unroll
  for (int q = 0; q < 4; ++q)
    hi4[q] = *(const float4*)&h[(size_t)row*Cc + ch*4 + q*32];
  __syncthreads();
  const int np8 = (cm + 7) >> 3;
  for (int p = 0; p < np8; ++p) {
    int slot = p*8 + s8;
    int sl = slot < cm ? slot : 0;
    int jj = cjs[wave][sl];
    const float* hj = h + (size_t)(b*Nn + jj)*Cc;
    float part = 0.f;
    #pragma unroll
    for (int q = 0; q < 4; ++q) {
      float4 v = *(const float4*)&hj[ch*4 + q*32];
      float e0 = hi4[q].x - v.x, e1 = hi4[q].y - v.y;
      float e2 = hi4[q].z - v.z, e3 = hi4[q].w - v.w;
      part = fmaf(e0, e0, part); part = fmaf(e1, e1, part);
      part = fmaf(e2, e2, part); part = fmaf(e3, e3, part);
    }
    part += __shfl_xor(part, 1, 64);
    part += __shfl_xor(part, 2, 64);
    part += __shfl_xor(part, 4, 64);
    if (ch == 0 && slot < cm) dsh[wave][slot] = part;
  }
  __syncthreads();
  int* op = (int*)(ws + IXOFF) + (size_t)row*KK;
  for (int cc = lane; cc < cm; cc += 64) {
    float dc = dsh[wave][cc];
    int jc = cjs[wave][cc];
    int rank = 0;
    #pragma unroll 1
    for (int m = 0; m < cm; ++m) {
      float dm = dsh[wave][m];
      int jm = cjs[wave][m];
      rank += (dm < dc || (dm == dc && jm < jc)) ? 1 : 0;
    }
    if (rank >= 1 && rank <= 16) op[rank - 1] = b*Nn + jc;
  }
}

// ---------------------------------------------------------------------------
// Kernel 6: fallback — queue-driven (expected empty). (unchanged)
__global__ __launch_bounds__(256) void k_fb(float* __restrict__ ws,
    const int* __restrict__ fbn, const int* __restrict__ fbq) {
  __shared__ float fd[4][17];
  __shared__ int   fj[4][17];
  __shared__ float his[128];
  const int wave = threadIdx.x >> 6, lane = threadIdx.x & 63;
  int nfb = fbn[0];
  nfb = (nfb < 0) ? 0 : ((nfb > NP) ? NP : nfb);
  for (int q = blockIdx.x; q < nfb; q += gridDim.x) {
    const int row = fbq[q];
    if ((unsigned)row >= (unsigned)NP) continue;
    const int b = row >> 11;
    const float* __restrict__ h = ws + HOFF + (size_t)b*Nn*Cc;
    if (threadIdx.x < 128) his[threadIdx.x] = h[(size_t)(row & (Nn-1))*Cc + threadIdx.x];
    __syncthreads();
    const float hi0 = his[lane], hi1 = his[lane + 64];
    float td[17]; int tj[17];
    #pragma unroll
    for (int s = 0; s < 17; ++s) { td[s] = 3.0e38f; tj[s] = 0x7FFFFFFF; }
    float cmax = 3.0e38f; int cjm = 0x7FFFFFFF, cpos = 0;
    const int jb = wave*512;
    #pragma unroll 1
    for (int it = 0; it < 256; ++it) {
      int j = jb + it*2;
      float a0 = h[(size_t)j*Cc + lane],     a1 = h[(size_t)j*Cc + lane + 64];
      float b0 = h[(size_t)(j+1)*Cc + lane], b1 = h[(size_t)(j+1)*Cc + lane + 64];
      float e0 = hi0 - a0, e1 = hi1 - a1, f0 = hi0 - b0, f1 = hi1 - b1;
      float p0 = e0*e0; p0 = fmaf(e1, e1, p0);
      float p1 = f0*f0; p1 = fmaf(f1, f1, p1);
      #pragma unroll
      for (int s2 = 1; s2 < 64; s2 <<= 1) {
        p0 += __shfl_xor(p0, s2, 64);
        p1 += __shfl_xor(p1, s2, 64);
      }
      #pragma unroll
      for (int u = 0; u < 2; ++u) {
        float d = u ? p1 : p0;
        int jd = j + u;
        if (d < cmax || (d == cmax && jd < cjm)) {
          #pragma unroll
          for (int s = 0; s < 17; ++s) {
            bool r = (s == cpos);
            td[s] = r ? d  : td[s];
            tj[s] = r ? jd : tj[s];
          }
          cmax = td[0]; cjm = tj[0]; cpos = 0;
          #pragma unroll
          for (int s = 1; s < 17; ++s)
            if (td[s] > cmax || (td[s] == cmax && tj[s] > cjm)) {
              cmax = td[s]; cjm = tj[s]; cpos = s;
            }
        }
      }
    }
    if (lane == 0) {
      #pragma unroll
      for (int s = 0; s < 17; ++s) { fd[wave][s] = td[s]; fj[wave][s] = tj[s]; }
    }
    __syncthreads();
    if (threadIdx.x < 68) {
      int e = threadIdx.x;
      float dc = fd[e / 17][e % 17];
      int   jc = fj[e / 17][e % 17];
      int rank = 0;
      #pragma unroll 1
      for (int m = 0; m < 68; ++m) {
        float dm = fd[m / 17][m % 17];
        int jm = fj[m / 17][m % 17];
        rank += (dm < dc || (dm == dc && jm < jc)) ? 1 : 0;
      }
      if (rank >= 1 && rank <= 16) {
        int* op = (int*)(ws + IXOFF) + (size_t)row*KK;
        op[rank - 1] = b*Nn + jc;
      }
    }
    __syncthreads();
  }
}

// ---------------------------------------------------------------------------
// Kernel 7: MFMA per-point MLP, weights in padded LDS. Per-nt FUSED pipeline
// (W2-MFMA -> softmax -> Wx2-MFMA -> aggregate -> store per channel tile):
// kills the wl[8] 32-VGPR array; __launch_bounds__(256,4) caps VGPR<=128 so
// LDS (53KB -> 3 blocks/CU = 12 waves) is the residency limit, not VGPRs.
// 16 points/block (4/wave), grid 1024, XCD swizzle kept (blk&7 = batch).
#define W2S_STRIDE  72    // shorts per row (64 + 8): 144B, 16B-aligned
#define WX2S_STRIDE 136   // shorts per row (128 + 8): 272B, 16B-aligned
__global__ __launch_bounds__(256, 4) void k_mlp(
    const float* __restrict__ b1v, const float* __restrict__ bx2,
    const unsigned short* __restrict__ w2t, const unsigned short* __restrict__ wx2t,
    const float* __restrict__ x, float* __restrict__ out,
    float* __restrict__ ws) {
  __shared__ unsigned short w2s[128*W2S_STRIDE];     // 18432 B
  __shared__ unsigned short wx2s[128*WX2S_STRIDE];   // 34816 B
  const int wave = threadIdx.x >> 6, lane = threadIdx.x & 63;
  const int l15 = lane & 15, l4 = lane >> 4;
  const int blk = blockIdx.x;
  const int bb = blk & 7;                         // batch (XCD-local)
  const int nbase = bb*Nn + (blk >> 3)*16 + wave*4;

  // stage weights into padded LDS (coalesced global reads)
  for (int i = threadIdx.x*8; i < 128*64; i += 256*8) {
    int j = i >> 6, k = i & 63;
    *(bf16x8*)&w2s[j*W2S_STRIDE + k] = *(const bf16x8*)&w2t[i];
  }
  for (int i = threadIdx.x*8; i < 128*128; i += 256*8) {
    int j = i >> 7, k = i & 127;
    *(bf16x8*)&wx2s[j*WX2S_STRIDE + k] = *(const bf16x8*)&wx2t[i];
  }

  // hoist wave-invariant vectors
  float4 b1f[4];
  #pragma unroll
  for (int c = 0; c < 2; ++c) {
    b1f[c*2]     = *(const float4*)(b1v + c*32 + l4*8);
    b1f[c*2 + 1] = *(const float4*)(b1v + c*32 + l4*8 + 4);
  }
  float bxv[8], lsv[8];
  #pragma unroll
  for (int nt = 0; nt < 8; ++nt) {
    bxv[nt] = bx2[nt*16 + l15];
    lsv[nt] = ws[LSOFF + bb*Cc + nt*16 + l15];
  }
  __syncthreads();

  const int* __restrict__ ipg = (const int*)(ws + IXOFF);
  const float* __restrict__ A1 = ws + A1OFF;
  int mk = ipg[(size_t)nbase*KK + l15];           // first point's gather index

  #pragma unroll 1
  for (int p = 0; p < 4; ++p) {
    const int n = nbase + p;
    int mk_next = (p < 3) ? ipg[(size_t)(n + 1)*KK + l15] : 0;

    // --- gather phase ---
    const float* a1m = A1 + (size_t)mk*F2;
    const float* a1n = A1 + (size_t)n*F2;
    bf16x8 hwA[2];
    #pragma unroll
    for (int c = 0; c < 2; ++c) {
      int off = c*32 + l4*8;
      float4 p0 = *(const float4*)(a1m + off), p1 = *(const float4*)(a1m + off + 4);
      float4 q0 = *(const float4*)(a1n + off), q1 = *(const float4*)(a1n + off + 4);
      float4 b0 = b1f[c*2], b1_ = b1f[c*2 + 1];
      bf16x8 r;
      r[0] = (short)f2bf(lrelu(p0.x - q0.x + b0.x));
      r[1] = (short)f2bf(lrelu(p0.y - q0.y + b0.y));
      r[2] = (short)f2bf(lrelu(p0.z - q0.z + b0.z));
      r[3] = (short)f2bf(lrelu(p0.w - q0.w + b0.w));
      r[4] = (short)f2bf(lrelu(p1.x - q1.x + b1_.x));
      r[5] = (short)f2bf(lrelu(p1.y - q1.y + b1_.y));
      r[6] = (short)f2bf(lrelu(p1.z - q1.z + b1_.z));
      r[7] = (short)f2bf(lrelu(p1.w - q1.w + b1_.w));
      hwA[c] = r;
    }
    const float* adm = ws + ADOFF + (size_t)mk*Cc;
    const float* hxb = ws + HXOFF + (size_t)n*Cc;
    bf16x8 hxA[4];
    #pragma unroll
    for (int c = 0; c < 4; ++c) {
      int off = c*32 + l4*8;
      float4 p0 = *(const float4*)(adm + off), p1 = *(const float4*)(adm + off + 4);
      float4 q0 = *(const float4*)(hxb + off), q1 = *(const float4*)(hxb + off + 4);
      bf16x8 r;
      r[0] = (short)f2bf(lrelu(p0.x + q0.x));
      r[1] = (short)f2bf(lrelu(p0.y + q0.y));
      r[2] = (short)f2bf(lrelu(p0.z + q0.z));
      r[3] = (short)f2bf(lrelu(p0.w + q0.w));
      r[4] = (short)f2bf(lrelu(p1.x + q1.x));
      r[5] = (short)f2bf(lrelu(p1.y + q1.y));
      r[6] = (short)f2bf(lrelu(p1.z + q1.z));
      r[7] = (short)f2bf(lrelu(p1.w + q1.w));
      hxA[c] = r;
    }

    // --- fused per-channel-tile: W2 GEMM -> softmax -> Wx2 GEMM -> agg ---
    #pragma unroll
    for (int nt = 0; nt < 8; ++nt) {
      f32x4 wv = {0,0,0,0};
      wv = __builtin_amdgcn_mfma_f32_16x16x32_bf16(hwA[0],
              *(const bf16x8*)&w2s[(nt*16 + l15)*W2S_STRIDE + l4*8], wv, 0, 0, 0);
      wv = __builtin_amdgcn_mfma_f32_16x16x32_bf16(hwA[1],
              *(const bf16x8*)&w2s[(nt*16 + l15)*W2S_STRIDE + 32 + l4*8], wv, 0, 0, 0);
      float mx = fmaxf(fmaxf(wv[0], wv[1]), fmaxf(wv[2], wv[3]));
      mx = fmaxf(mx, __shfl_xor(mx, 16, 64));
      mx = fmaxf(mx, __shfl_xor(mx, 32, 64));
      float e0 = __expf(wv[0] - mx), e1 = __expf(wv[1] - mx);
      float e2 = __expf(wv[2] - mx), e3 = __expf(wv[3] - mx);
      float sm = e0 + e1 + e2 + e3;
      sm += __shfl_xor(sm, 16, 64);
      sm += __shfl_xor(sm, 32, 64);
      float rs = 1.0f / sm;

      f32x4 acc = {0,0,0,0};
      #pragma unroll
      for (int c = 0; c < 4; ++c)
        acc = __builtin_amdgcn_mfma_f32_16x16x32_bf16(hxA[c],
                *(const bf16x8*)&wx2s[(nt*16 + l15)*WX2S_STRIDE + c*32 + l4*8],
                acc, 0, 0, 0);
      float bx = bxv[nt];
      float ap = (e0*(acc[0] + bx) + e1*(acc[1] + bx)
                + e2*(acc[2] + bx) + e3*(acc[3] + bx)) * rs;
      ap += __shfl_xor(ap, 16, 64);
      ap += __shfl_xor(ap, 32, 64);
      if (l4 == 0) {
        size_t xo = (size_t)n*Cc + nt*16 + l15;
        out[xo] = fmaf(ap, lsv[nt], x[xo]);
      }
    }
    mk = mk_next;
  }
}

// ---------------------------------------------------------------------------
extern "C" void kernel_launch(void* const* d_in, const int* in_sizes, int n_in,
                              void* d_out, int out_size, void* d_ws, size_t ws_size,
                              hipStream_t stream) {
  const float* x   = (const float*)d_in[0];
  const float* w   = (const float*)d_in[1];
  const float* Wg  = (const float*)d_in[2];
  const float* Wb  = (const float*)d_in[3];
  const float* W1  = (const float*)d_in[4];
  const float* b1  = (const float*)d_in[5];
  const float* W2  = (const float*)d_in[6];
  const float* Wx1 = (const float*)d_in[8];
  const float* bx1 = (const float*)d_in[9];
  const float* Wx2 = (const float*)d_in[10];
  const float* bx2 = (const float*)d_in[11];
  const float* Wls = (const float*)d_in[12];
  const float* bls = (const float*)d_in[13];
  float* out = (float*)d_out;
  float* ws  = (float*)d_ws;
  unsigned short* hi_g = (unsigned short*)((char*)d_ws + HIBYTES);
  unsigned short* w2t  = (unsigned short*)((char*)d_ws + W2TBYTES);
  unsigned short* wx2t = (unsigned short*)((char*)d_ws + WX2TBYTES);
  unsigned short* cand = (unsigned short*)((char*)d_ws + CANDBYTES);
  int* cnt_g = (int*)(ws + CNTOFF);
  int* fbn   = (int*)(ws + FBNOFF);
  int* fbq   = (int*)(ws + FBQOFF);

  int CAP = 0;
  if (ws_size > CANDBYTES) {
    size_t c = (ws_size - CANDBYTES) / ((size_t)NP * 2);
    CAP = (c >= CAPMAX) ? CAPMAX : (int)c;
  }

  k_pervec<<<Bz, 512, 0, stream>>>(w, Wg, Wb, Wls, bls, ws);
  k_wprep<<<64, 256, 0, stream>>>(W2, Wx2, w2t, wx2t);
  k_h<<<NP, 64, 0, stream>>>(x, ws, hi_g, fbn);
  k_pre<<<NP/4, 128, 0, stream>>>(W1, Wx1, bx1, ws);
  k_filter<<<512, 512, 0, stream>>>(ws, hi_g, cand, cnt_g, CAP);
  k_refine<<<NP/4, 256, 0, stream>>>(ws, cand, cnt_g, fbn, fbq, CAP);
  k_fb<<<256, 256, 0, stream>>>(ws, fbn, fbq);
  k_mlp<<<1024, 256, 0, stream>>>(b1, bx2, w2t, wx2t, x, out, ws);
}